// Round 7
// baseline (232.319 us; speedup 1.0000x reference)
//
#include <hip/hip_runtime.h>
#include <hip/hip_bf16.h>

typedef __attribute__((ext_vector_type(8))) short s8v;
typedef __attribute__((ext_vector_type(4))) float f4v;
typedef __attribute__((ext_vector_type(16))) float f16v;
typedef __attribute__((ext_vector_type(4))) unsigned u4v;

typedef __attribute__((address_space(1))) const void as1_void;
typedef __attribute__((address_space(3))) void as3_void;

__device__ __forceinline__ void gl16(const void* g, void* l) {
  __builtin_amdgcn_global_load_lds((as1_void*)g, (as3_void*)l, 16, 0, 0);
}

__device__ __forceinline__ float b2f(int u) {
  union { float f; unsigned i; } c; c.i = ((unsigned)(u & 0xFFFF)) << 16; return c.f;
}
__device__ __forceinline__ unsigned short f2b(float f) {   // RNE
  union { float f; unsigned i; } c; c.f = f;
  unsigned r = c.i + 0x7FFFu + ((c.i >> 16) & 1u);
  return (unsigned short)(r >> 16);
}
__device__ __forceinline__ unsigned pk2(float lo, float hi) {  // 2xbf16 pack
  unsigned u;
  asm("v_cvt_pk_bf16_f32 %0, %1, %2" : "=v"(u) : "v"(lo), "v"(hi));
  return u;
}
__device__ __forceinline__ float max3f(float a, float b, float c) {
  float d;
  asm("v_max3_f32 %0, %1, %2, %3" : "=v"(d) : "v"(a), "v"(b), "v"(c));
  return d;
}

#define MFMA16(a, b, c) __builtin_amdgcn_mfma_f32_16x16x32_bf16((a), (b), (c), 0, 0, 0)
#define MFMA32(a, b, c) __builtin_amdgcn_mfma_f32_32x32x16_bf16((a), (b), (c), 0, 0, 0)

// ---------------- fused prep: all weight converts (+gu interleave) + rope tables ----------------
struct Seg { const float* src; unsigned short* dst; int K; int N; int nbn; int nblocks; int mode; };
struct PrepArgs { Seg seg[8]; float* ct; float* st; };

__global__ __launch_bounds__(256) void prep_k(PrepArgs a) {
  int b = blockIdx.x, si = 0;
  while (si < 7 && b >= a.seg[si].nblocks) { b -= a.seg[si].nblocks; ++si; }
  const Seg s = a.seg[si];
  const int tid = threadIdx.x;
  if (s.mode == 3) {               // rope tables [4096][32]
    const int t = b * 256 + tid;
    const int sq = t >> 5, d = t & 31;
    const float inv = powf(10000.0f, -(float)d * (1.0f / 32.0f));
    const float ang = (float)sq * inv;
    a.ct[t] = cosf(ang);
    a.st[t] = sinf(ang);
    return;
  }
  __shared__ float tile[32][33];
  const int tx = tid & 31, ty = tid >> 5;
  const int bn = b % s.nbn, bk = b / s.nbn;
#pragma unroll
  for (int i = 0; i < 32; i += 8)
    tile[ty + i][tx] = s.src[(size_t)(bk * 32 + ty + i) * s.N + bn * 32 + tx];
  __syncthreads();
#pragma unroll
  for (int i = 0; i < 32; i += 8) {
    int row;
    if (s.mode == 0)      row = bn * 32 + ty + i;
    else                  row = bn * 64 + (s.mode == 2 ? 32 : 0) + ty + i;
    s.dst[(size_t)row * s.K + bk * 32 + tx] = f2b(tile[tx][ty + i]);
  }
}

// ---------------- RMSNorm: fp32 in -> bf16 out, D=768 ----------------
__global__ __launch_bounds__(256) void rmsnorm_k(const float* __restrict__ x,
    const float* __restrict__ w, unsigned short* __restrict__ out) {
  const int row = blockIdx.x, tid = threadIdx.x;
  const float* xr = x + (size_t)row * 768;
  float v0 = xr[tid], v1 = xr[tid + 256], v2 = xr[tid + 512];
  float ss = v0 * v0 + v1 * v1 + v2 * v2;
#pragma unroll
  for (int m = 1; m < 64; m <<= 1) ss += __shfl_xor(ss, m, 64);
  __shared__ float sred[4];
  if ((tid & 63) == 0) sred[tid >> 6] = ss;
  __syncthreads();
  const float tot = sred[0] + sred[1] + sred[2] + sred[3];
  const float rn = rsqrtf(tot * (1.0f / 768.0f) + 1e-6f);
  unsigned short* orow = out + (size_t)row * 768;
  orow[tid]       = f2b(v0 * rn * w[tid]);
  orow[tid + 256] = f2b(v1 * rn * w[tid + 256]);
  orow[tid + 512] = f2b(v2 * rn * w[tid + 512]);
}

// ---------------- GEMM: C[M,N] = A[M,K](bf16) * Bt[N,K](bf16)^T ----------------
// 3-buffer LDS pipeline, counted vmcnt (loads span 2 K-steps), raw s_barrier.
// EPI 1: fp32 store + fp32 residual add
// EPI 2: bf16 store + RoPE on bn<12; bn<6 (q region) additionally scaled by 0.125*log2e
// EPI 3: silu(gate)*up from 32-interleaved B rows -> bf16, ldc=2048
template <int EPI, int BN>
__global__ __launch_bounds__(256) void gemm_bt(const unsigned short* __restrict__ A,
    const unsigned short* __restrict__ Bt, unsigned short* __restrict__ Cb,
    float* __restrict__ Cf, const float* __restrict__ R, int K, int ldc,
    const float* __restrict__ ct, const float* __restrict__ st) {
  constexpr int ABYTES = 128 * 32 * 2;
  constexpr int BBYTES = BN * 32 * 2;
  constexpr int MR = (BN == 128) ? 4 : 2;
  __shared__ unsigned short As[3 * 128 * 32];
  __shared__ unsigned short Bs[3 * BN * 32];
  const int tid = threadIdx.x;
  const int lane = tid & 63, wid = tid >> 6;
  const int wrow = (BN == 128) ? (wid >> 1) * 64 : wid * 32;
  const int wcol = (BN == 128) ? (wid & 1) * 64 : 0;
  const int l15 = lane & 15, l4 = lane >> 4;
  const int bm = blockIdx.y, bn = blockIdx.x;

  f4v acc[MR][4] = {};

  const int o0 = tid * 16, o1 = tid * 16 + 4096;
  const int r0 = o0 >> 6, c0 = o0 & 63;
  const int r1 = o1 >> 6, c1 = o1 & 63;
  const size_t ldab = (size_t)K * 2;
  const char* Abyte = (const char*)A;
  const char* Bbyte = (const char*)Bt;
  const size_t a0 = (size_t)(bm * 128 + r0) * ldab + c0;
  const size_t a1 = (size_t)(bm * 128 + r1) * ldab + c1;
  const size_t b0 = (size_t)(bn * BN + r0) * ldab + c0;
  const size_t b1 = (size_t)(bn * BN + r1) * ldab + c1;   // used only when BN==128
  char* AsB = (char*)As;
  char* BsB = (char*)Bs;
  const int uoff = wid << 10;

#define STAGEK(I, SL) do { const size_t kb = (size_t)(I) * 64;                 \
    char* Aw = AsB + (SL) * ABYTES;                                            \
    char* Bw = BsB + (SL) * BBYTES;                                            \
    gl16(Abyte + a0 + kb, Aw + uoff);                                          \
    gl16(Abyte + a1 + kb, Aw + uoff + 4096);                                   \
    gl16(Bbyte + b0 + kb, Bw + uoff);                                          \
    if constexpr (BN == 128) gl16(Bbyte + b1 + kb, Bw + uoff + 4096); } while (0)

  const int NI = K >> 5;
  STAGEK(0, 0);
  STAGEK(1, 1);
  int sel = 0, nsl = 2;

  for (int i = 0; i < NI; ++i) {
    if (i < NI - 1) {                       // stage(i) landed; stage(i+1) may stay in flight
      if constexpr (BN == 128) asm volatile("s_waitcnt vmcnt(4)" ::: "memory");
      else                     asm volatile("s_waitcnt vmcnt(3)" ::: "memory");
    } else {
      asm volatile("s_waitcnt vmcnt(0)" ::: "memory");
    }
    __builtin_amdgcn_s_barrier();           // all waves: stage(i) visible, buf(i-1) free
    __builtin_amdgcn_sched_barrier(0);
    if (i + 2 < NI) STAGEK(i + 2, nsl);     // overwrite buf(i-1)'s slot, stays in flight
    const char* Ar = AsB + sel * ABYTES;
    const char* Br = BsB + sel * BBYTES;
    s8v af[MR], bf[4];
#pragma unroll
    for (int m = 0; m < MR; ++m)
      af[m] = *(const s8v*)(Ar + (wrow + m * 16 + l15) * 64 + l4 * 16);
#pragma unroll
    for (int n = 0; n < 4; ++n)
      bf[n] = *(const s8v*)(Br + (wcol + n * 16 + l15) * 64 + l4 * 16);
    __builtin_amdgcn_s_setprio(1);
#pragma unroll
    for (int m = 0; m < MR; ++m)
#pragma unroll
      for (int n = 0; n < 4; ++n) acc[m][n] = MFMA16(af[m], bf[n], acc[m][n]);
    __builtin_amdgcn_s_setprio(0);
    sel = (sel == 2) ? 0 : sel + 1;
    nsl = (nsl == 2) ? 0 : nsl + 1;
  }
#undef STAGEK

  const int row0 = bm * 128 + wrow;
  const int col0 = bn * BN + wcol;

  if (EPI == 2 && bn < 12) {       // RoPE in-register: pair (m,n) with (m,n+2)
#pragma unroll
    for (int m = 0; m < MR; ++m)
#pragma unroll
      for (int r = 0; r < 4; ++r) {
        const int row = row0 + m * 16 + l4 * 4 + r;
#pragma unroll
        for (int n = 0; n < 2; ++n) {
          const int d = n * 16 + l15;
          const float c  = ct[row * 32 + d];
          const float sn = st[row * 32 + d];
          const float aa = acc[m][n][r], bb = acc[m][n + 2][r];
          acc[m][n][r]     = aa * c - bb * sn;
          acc[m][n + 2][r] = bb * c + aa * sn;
        }
      }
  }
  if (EPI == 2 && bn < 6) {        // pre-scale Q by 0.125*log2(e) for exp2-domain softmax
    const float QSC = 0.18033688011112042f;
#pragma unroll
    for (int m = 0; m < MR; ++m)
#pragma unroll
      for (int n = 0; n < 4; ++n)
#pragma unroll
        for (int r = 0; r < 4; ++r) acc[m][n][r] *= QSC;
  }

  if (EPI == 3) {                  // silu(g)*u, g at n<2, u at n+2
    const int wcx = wcol >> 6;
    const int colb = (bn * 2 + wcx) * 32;
#pragma unroll
    for (int m = 0; m < MR; ++m)
#pragma unroll
      for (int n = 0; n < 2; ++n)
#pragma unroll
        for (int r = 0; r < 4; ++r) {
          const int row = row0 + m * 16 + l4 * 4 + r;
          const float g = acc[m][n][r], u = acc[m][n + 2][r];
          const float val = g * u / (1.0f + __expf(-g));
          Cb[(size_t)row * 2048 + colb + n * 16 + l15] = f2b(val);
        }
    return;
  }

#pragma unroll
  for (int m = 0; m < MR; ++m)
#pragma unroll
    for (int n = 0; n < 4; ++n)
#pragma unroll
      for (int r = 0; r < 4; ++r) {
        const int row = row0 + m * 16 + l4 * 4 + r;
        const int col = col0 + n * 16 + l15;
        const float v = acc[m][n][r];
        if (EPI == 1) {
          Cf[(size_t)row * ldc + col] = v + R[(size_t)row * ldc + col];
        } else {
          Cb[(size_t)row * ldc + col] = f2b(v);
        }
      }
}

// ---------------- causal flash attention: merged key-parity halves, in-block combine ----------------
// grid (p=32, h=12), 512 threads. Waves 0-3 = kh0 half, waves 4-7 = kh1 half; each half
// has its own double-buffered K/V staging. Per half: long waves (qbA) / short waves (qbB)
// interleaved so each SIMD gets one long + one short. Uniform barrier count NT = qbA/2+1.
// Final: kh1 partials -> LDS, kh0 merges + normalizes, bf16 O staged in LDS, coop store.
__global__ __launch_bounds__(512, 4) void flash_k(const unsigned short* __restrict__ qkv,
    unsigned short* __restrict__ out) {
  const int p = blockIdx.x, h = blockIdx.y;
  const int qbA = 63 - p, qbB = p;
  const int tid = threadIdx.x;
  const int wv = tid >> 6, lane = tid & 63;
  const int l31 = lane & 31, h8 = lane >> 5;
  const int h4 = wv >> 2, idx = wv & 3;
  const bool roleL = ((idx & 1) == h4);     // long(qbA) role, SIMD-mixed across halves
  const int rowhalf = idx >> 1;
  const int myqb = roleL ? qbA : qbB;
  const int qrel = rowhalf * 32 + l31;
  const int q_abs = myqb * 64 + qrel;

  __shared__ char smem[73728];
#define KSB(hf, bf) ((unsigned short*)(smem + ((((hf) * 2 + (bf)) * 2 + 0) * 9216)))
#define VTB(hf, bf) ((unsigned short*)(smem + ((((hf) * 2 + (bf)) * 2 + 1) * 9216)))

  const unsigned short* qp = qkv + h * 64;
  const unsigned short* kp = qkv + 768 + h * 64;
  const unsigned short* vp = qkv + 1536 + h * 64;

  s8v qf[4];
#pragma unroll
  for (int c = 0; c < 4; ++c)
    qf[c] = *(const s8v*)(qp + (size_t)q_abs * 2304 + c * 16 + h8 * 8);

  f16v o0 = {}, o1 = {};
  float m_s = -1e30f, l_s = 0.f;

  const int tid2 = tid & 255;
  const int krow = tid2 >> 3, kc = (tid2 & 7) * 8;
  const int vj = tid2 & 31, vd0 = (tid2 >> 5) * 8;

  s8v ka, kb, va, vb;
#define LOADT(T) do { const size_t k0n = (size_t)(T) * 64;                    \
    ka = *(const s8v*)(kp + (k0n + krow) * 2304 + kc);                        \
    kb = *(const s8v*)(kp + (k0n + krow + 32) * 2304 + kc);                   \
    va = *(const s8v*)(vp + (k0n + 2 * vj) * 2304 + vd0);                     \
    vb = *(const s8v*)(vp + (k0n + 2 * vj + 1) * 2304 + vd0); } while (0)
#define WRITET(BUF) do {                                                      \
    unsigned short* ksw = KSB(h4, BUF);                                       \
    *(s8v*)(ksw + krow * 72 + kc) = ka;                                       \
    *(s8v*)(ksw + (krow + 32) * 72 + kc) = kb;                                \
    unsigned* vtw = (unsigned*)(VTB(h4, BUF) + (size_t)vd0 * 72 + 2 * vj);    \
    _Pragma("unroll")                                                         \
    for (int i = 0; i < 8; ++i)                                               \
      vtw[i * 36] = ((unsigned)(unsigned short)va[i]) |                       \
                    (((unsigned)(unsigned short)vb[i]) << 16); } while (0)

  LOADT(h4);
  WRITET(0);
  if (h4 + 2 <= qbA) LOADT(h4 + 2);
  __syncthreads();

  const int NT = (qbA >> 1) + 1;            // uniform iteration/barrier count for all 8 waves
  for (int tt = 0; tt < NT; ++tt) {
    const int t = 2 * tt + h4;
    const int cur = tt & 1;
    if (t <= myqb) {
      const unsigned short* Ksr = KSB(h4, cur);
      const unsigned short* Vtr = VTB(h4, cur);
      // S^T[key][q] = K * Q^T (swapped); scores arrive in log2 domain (Q pre-scaled)
      f16v s0 = {}, s1 = {};
      __builtin_amdgcn_s_setprio(1);
#pragma unroll
      for (int c = 0; c < 4; ++c) {
        const s8v kf0 = *(const s8v*)(Ksr + l31 * 72 + c * 16 + h8 * 8);
        const s8v kf1 = *(const s8v*)(Ksr + (32 + l31) * 72 + c * 16 + h8 * 8);
        s0 = MFMA32(kf0, qf[c], s0);
        s1 = MFMA32(kf1, qf[c], s1);
      }
      __builtin_amdgcn_s_setprio(0);
      if (t == myqb) {                      // diagonal tile: causal mask
#pragma unroll
        for (int r = 0; r < 16; ++r) {
          const int koff = (r & 3) + 8 * (r >> 2) + 4 * h8;
          if (koff > qrel) s0[r] = -1e30f;
          if (koff + 32 > qrel) s1[r] = -1e30f;
        }
      }
      // row max: max3 tree + one cross-half shuffle
      float u[8];
#pragma unroll
      for (int i = 0; i < 8; ++i)
        u[i] = fmaxf(max3f(s0[i], s0[i + 8], s1[i]), s1[i + 8]);
      float mloc = fmaxf(max3f(max3f(max3f(u[0], u[1], u[2]), u[3], u[4]), u[5], u[6]), u[7]);
      mloc = fmaxf(mloc, __shfl_xor(mloc, 32));
      if (__any(mloc > m_s + 11.0f)) {      // defer-max (log2 units)
        const float mn = fmaxf(m_s, mloc);
        const float corr = exp2f(m_s - mn);
        m_s = mn; l_s *= corr;
#pragma unroll
        for (int r = 0; r < 16; ++r) { o0[r] *= corr; o1[r] *= corr; }
      }
#pragma unroll
      for (int r = 0; r < 16; ++r) {
        s0[r] = exp2f(s0[r] - m_s);
        s1[r] = exp2f(s1[r] - m_s);
      }
      float sm[8];
#pragma unroll
      for (int i = 0; i < 8; ++i) sm[i] = (s0[i] + s0[i + 8]) + (s1[i] + s1[i + 8]);
#pragma unroll
      for (int i = 0; i < 4; ++i) sm[i] += sm[i + 4];
      float ps = (sm[0] + sm[1]) + (sm[2] + sm[3]);
      ps += __shfl_xor(ps, 32);
      l_s += ps;

      // pack P to bf16 pairs; cross-half redistribute into PV B-frags
      unsigned pk0[8], pk1[8];
#pragma unroll
      for (int g = 0; g < 4; ++g)
#pragma unroll
        for (int j = 0; j < 2; ++j) {
          pk0[g * 2 + j] = pk2(s0[g * 4 + 2 * j], s0[g * 4 + 2 * j + 1]);
          pk1[g * 2 + j] = pk2(s1[g * 4 + 2 * j], s1[g * 4 + 2 * j + 1]);
        }
      __builtin_amdgcn_s_setprio(1);
#pragma unroll
      for (int c = 0; c < 4; ++c) {
        const int g0 = (c & 1) * 2, g1 = g0 + 1;
        const unsigned pA0 = (c & 2) ? pk1[g0 * 2 + 0] : pk0[g0 * 2 + 0];
        const unsigned pA1 = (c & 2) ? pk1[g0 * 2 + 1] : pk0[g0 * 2 + 1];
        const unsigned pB0 = (c & 2) ? pk1[g1 * 2 + 0] : pk0[g1 * 2 + 0];
        const unsigned pB1 = (c & 2) ? pk1[g1 * 2 + 1] : pk0[g1 * 2 + 1];
        const unsigned t00 = __shfl_xor((int)pA0, 32);
        const unsigned t01 = __shfl_xor((int)pA1, 32);
        const unsigned t10 = __shfl_xor((int)pB0, 32);
        const unsigned t11 = __shfl_xor((int)pB1, 32);
        union { u4v u; s8v s; } pf;
        pf.u[0] = h8 ? t10 : pA0;
        pf.u[1] = h8 ? t11 : pA1;
        pf.u[2] = h8 ? pB0 : t00;
        pf.u[3] = h8 ? pB1 : t01;
        const s8v vf0 = *(const s8v*)(Vtr + l31 * 72 + c * 16 + h8 * 8);
        const s8v vf1 = *(const s8v*)(Vtr + (32 + l31) * 72 + c * 16 + h8 * 8);
        o0 = MFMA32(vf0, pf.s, o0);
        o1 = MFMA32(vf1, pf.s, o1);
      }
      __builtin_amdgcn_s_setprio(0);
    }
    if (t + 2 <= qbA) {
      WRITET(cur ^ 1);
      if (t + 4 <= qbA) LOADT(t + 4);
    }
    __syncthreads();                        // uniform: every wave, every iteration
  }
#undef LOADT
#undef WRITET

  // ---- in-block combine: kh1 -> LDS, kh0 merges; bf16 O staged; cooperative store ----
  float* fup = (float*)smem;                // 4 waves x 64 lanes x 32 f32 (32 KB)
  float* mup = (float*)(smem + 32768);      // 4 x 64 x {m,l}         (2 KB)
  if (h4) {
    const int base = (idx * 64 + lane) * 32;
#pragma unroll
    for (int r = 0; r < 16; ++r) { fup[base + r] = o0[r]; fup[base + 16 + r] = o1[r]; }
    mup[(idx * 64 + lane) * 2]     = m_s;
    mup[(idx * 64 + lane) * 2 + 1] = l_s;
  }
  __syncthreads();
  unsigned short* obuf = (unsigned short*)(smem + 36864);   // [128 q][72] bf16
  if (!h4) {
    const int pb = ((idx ^ 1) * 64 + lane);
    const float m2 = mup[pb * 2], l2 = mup[pb * 2 + 1];
    const float mx = fmaxf(m_s, m2);
    const float w0 = exp2f(m_s - mx), w1 = exp2f(m2 - mx);
    const float inv = 1.0f / (w0 * l_s + w1 * l2);
    const int Rr = (roleL ? 0 : 64) + qrel;
    const int fb = pb * 32;
#pragma unroll
    for (int r = 0; r < 16; ++r) {
      const int d0 = (r & 3) + 8 * (r >> 2) + 4 * h8;
      obuf[Rr * 72 + d0]      = f2b((w0 * o0[r] + w1 * fup[fb + r]) * inv);
      obuf[Rr * 72 + 32 + d0] = f2b((w0 * o1[r] + w1 * fup[fb + 16 + r]) * inv);
    }
  }
  __syncthreads();
  {
    const int Rr = tid >> 2, ds = (tid & 3) * 16;
    const int qb_o = (Rr < 64) ? qbA : qbB;
    const int qr = Rr & 63;
    unsigned short* dst = out + (size_t)(qb_o * 64 + qr) * 768 + h * 64 + ds;
    *(s8v*)dst       = *(const s8v*)(obuf + Rr * 72 + ds);
    *(s8v*)(dst + 8) = *(const s8v*)(obuf + Rr * 72 + ds + 8);
  }
#undef KSB
#undef VTB
}

extern "C" void kernel_launch(void* const* d_in, const int* in_sizes, int n_in,
                              void* d_out, int out_size, void* d_ws, size_t ws_size,
                              hipStream_t stream) {
  const float* x    = (const float*)d_in[0];
  const float* w_q  = (const float*)d_in[1];
  const float* w_k  = (const float*)d_in[2];
  const float* w_v  = (const float*)d_in[3];
  const float* w_o  = (const float*)d_in[4];
  const float* w_g  = (const float*)d_in[5];
  const float* w_u  = (const float*)d_in[6];
  const float* w_d  = (const float*)d_in[7];
  const float* w_n1 = (const float*)d_in[8];
  const float* w_n2 = (const float*)d_in[9];
  (void)in_sizes; (void)n_in; (void)out_size; (void)ws_size;

  char* ws = (char*)d_ws;
  size_t off = 0;
  auto alloc = [&](size_t bytes) { char* p = ws + off; off += (bytes + 255) & ~(size_t)255; return p; };
  unsigned short* wqkvT = (unsigned short*)alloc(2304ull * 768 * 2);
  unsigned short* woT   = (unsigned short*)alloc(768ull * 768 * 2);
  unsigned short* wguT  = (unsigned short*)alloc(4096ull * 768 * 2);
  unsigned short* wdT   = (unsigned short*)alloc(768ull * 2048 * 2);
  float* ct             = (float*)alloc(4096ull * 32 * 4);
  float* st             = (float*)alloc(4096ull * 32 * 4);
  unsigned short* xn    = (unsigned short*)alloc(4096ull * 768 * 2);
  unsigned short* qkv   = (unsigned short*)alloc(4096ull * 2304 * 2);
  unsigned short* attn  = (unsigned short*)alloc(4096ull * 768 * 2);
  float* hbuf           = (float*)alloc(4096ull * 768 * 4);
  unsigned short* ybuf  = (unsigned short*)alloc(4096ull * 768 * 2);
  unsigned short* ffn   = (unsigned short*)alloc(4096ull * 2048 * 2);

  PrepArgs pa;
  pa.seg[0] = { w_q, wqkvT,                 768,  768, 24,  576, 0 };
  pa.seg[1] = { w_k, wqkvT + 768 * 768,     768,  768, 24,  576, 0 };
  pa.seg[2] = { w_v, wqkvT + 2 * 768 * 768, 768,  768, 24,  576, 0 };
  pa.seg[3] = { w_o, woT,                   768,  768, 24,  576, 0 };
  pa.seg[4] = { w_g, wguT,                  768, 2048, 64, 1536, 1 };
  pa.seg[5] = { w_u, wguT,                  768, 2048, 64, 1536, 2 };
  pa.seg[6] = { w_d, wdT,                  2048,  768, 24, 1536, 0 };
  pa.seg[7] = { nullptr, nullptr, 0, 0, 0, 512, 3 };
  pa.ct = ct; pa.st = st;
  const int prep_blocks = 576 * 4 + 1536 * 3 + 512;   // 7424

  prep_k<<<prep_blocks, 256, 0, stream>>>(pa);
  rmsnorm_k<<<4096, 256, 0, stream>>>(x, w_n1, xn);
  gemm_bt<2, 128><<<dim3(18, 32), 256, 0, stream>>>(xn, wqkvT, qkv, nullptr, nullptr, 768, 2304, ct, st);
  flash_k<<<dim3(32, 12), 512, 0, stream>>>(qkv, attn);
  gemm_bt<1, 64><<<dim3(12, 32), 256, 0, stream>>>(attn, woT, nullptr, hbuf, x, 768, 768, nullptr, nullptr);
  rmsnorm_k<<<4096, 256, 0, stream>>>(hbuf, w_n2, ybuf);
  gemm_bt<3, 128><<<dim3(32, 32), 256, 0, stream>>>(ybuf, wguT, ffn, nullptr, nullptr, 768, 2048, nullptr, nullptr);
  gemm_bt<1, 64><<<dim3(12, 32), 256, 0, stream>>>(ffn, wdT, nullptr, (float*)d_out, hbuf, 2048, 768, nullptr, nullptr);
}